// Round 5
// baseline (1715.874 us; speedup 1.0000x reference)
//
#include <hip/hip_runtime.h>
#include <math.h>

#define BS_    256
#define FEAT_  2048
#define EMB_   512
#define MEM_   1024
#define VOCAB_ 10000
#define TT_    32
#define NSTEP  31
#define VT_    128
#define NTV_   79      // ceil(10000/128)
#define MROWS_ 7936    // 31*256

typedef unsigned short u16;
typedef __bf16 bf16x8 __attribute__((ext_vector_type(8)));
typedef float  f32x4  __attribute__((ext_vector_type(4)));
typedef u16    u16x8  __attribute__((ext_vector_type(8)));
typedef u16    u16x4  __attribute__((ext_vector_type(4)));
typedef bf16x8 __attribute__((may_alias)) bf16x8_ma;
typedef u16x8  __attribute__((may_alias)) u16x8_ma;
typedef u16x4  __attribute__((may_alias)) u16x4_ma;
typedef float4 __attribute__((may_alias)) float4_ma;

__device__ __forceinline__ u16 f2bf(float f) {
  unsigned u = __float_as_uint(f);
  u += 0x7FFFu + ((u >> 16) & 1u);
  return (u16)(u >> 16);
}

__device__ __forceinline__ void async16(const void* g, void* s) {
  __builtin_amdgcn_global_load_lds((const __attribute__((address_space(1))) void*)g,
                                   (__attribute__((address_space(3))) void*)s, 16, 0, 0);
}

__device__ __forceinline__ float redsum16(float v) {
#pragma unroll
  for (int m = 1; m < 16; m <<= 1) v += __shfl_xor(v, m, 64);
  return v;
}
__device__ __forceinline__ float sigmoidf_(float x) { return 1.0f / (1.0f + __expf(-x)); }
// fast tanh via exp2-based __expf; exact at saturation
__device__ __forceinline__ float tanhf_(float x) {
  float e = __expf(2.0f * x);
  return 1.0f - 2.0f / (e + 1.0f);
}

// ---------------------------------------------------------------------------
// fp32 -> bf16 bulk convert
// ---------------------------------------------------------------------------
__global__ __launch_bounds__(256) void cvt_bf16_k(const float* __restrict__ in,
                                                  u16* __restrict__ out, int n4) {
  int i = blockIdx.x * 256 + threadIdx.x;
  if (i >= n4) return;
  float4 v = ((const float4_ma*)in)[i];
  u16x4 o = { f2bf(v.x), f2bf(v.y), f2bf(v.z), f2bf(v.w) };
  *(u16x4_ma*)(out + (size_t)i * 4) = o;
}

// ---------------------------------------------------------------------------
// Gate-permuted weight conversion: permuted row r -> source row (r&3)*1024+(r>>2)
// ---------------------------------------------------------------------------
__global__ __launch_bounds__(128) void cvt_permute_k(
    const float* __restrict__ W_ih, const float* __restrict__ W_hh,
    const float* __restrict__ b_ih, const float* __restrict__ b_hh,
    u16* __restrict__ WPih, u16* __restrict__ WPhh, float* __restrict__ biasP) {
  int r = blockIdx.x, tid = threadIdx.x;
  int u = r >> 2, g = r & 3, s = g * 1024 + u;
  {
    float4 v = *(const float4_ma*)(W_ih + (size_t)s * EMB_ + tid * 4);
    u16x4 o = { f2bf(v.x), f2bf(v.y), f2bf(v.z), f2bf(v.w) };
    *(u16x4_ma*)(WPih + (size_t)r * EMB_ + tid * 4) = o;
  }
#pragma unroll
  for (int h = 0; h < 2; ++h) {
    int idx = h * 512 + tid * 4;
    float4 v = *(const float4_ma*)(W_hh + (size_t)s * MEM_ + idx);
    u16x4 o = { f2bf(v.x), f2bf(v.y), f2bf(v.z), f2bf(v.w) };
    *(u16x4_ma*)(WPhh + (size_t)r * MEM_ + idx) = o;
  }
  if (tid == 0) biasP[r] = b_ih[s] + b_hh[s];
}

// ---------------------------------------------------------------------------
// Gather all step embeddings to bf16
// ---------------------------------------------------------------------------
__global__ __launch_bounds__(256) void gather_x_k(const float* __restrict__ emb,
                                                  const int* __restrict__ caption,
                                                  u16* __restrict__ X) {
  int i = blockIdx.x * 256 + threadIdx.x;
  int e4 = (i & 127) * 4;
  int b  = (i >> 7) & 255;
  int t  = i >> 15;
  int cap = caption[b * TT_ + t];
  float4 v = *(const float4_ma*)(emb + (size_t)cap * EMB_ + e4);
  u16x4 o = { f2bf(v.x), f2bf(v.y), f2bf(v.z), f2bf(v.w) };
  *(u16x4_ma*)(X + ((size_t)(t * 256 + b) * EMB_ + e4)) = o;
}

// ---------------------------------------------------------------------------
// fp32 vector GEMM fallback for init
// ---------------------------------------------------------------------------
__global__ __launch_bounds__(256) void gemm_nt_bias_k(
    const float* __restrict__ A, const float* __restrict__ B,
    const float* __restrict__ bias, float* __restrict__ C, u16* __restrict__ Cb,
    int M, int N, int K) {
  __shared__ float As[16][65];
  __shared__ float Bs[16][65];
  int tid = threadIdx.x;
  int bx = blockIdx.x, by = blockIdx.y;
  int tx = tid & 15, ty = tid >> 4;
  float acc[4][4] = {};
  for (int k0 = 0; k0 < K; k0 += 16) {
#pragma unroll
    for (int i = 0; i < 4; ++i) {
      int idx = tid + i * 256;
      As[idx & 15][idx >> 4] = A[(size_t)(by * 64 + (idx >> 4)) * K + k0 + (idx & 15)];
    }
#pragma unroll
    for (int i = 0; i < 4; ++i) {
      int idx = tid + i * 256;
      Bs[idx & 15][idx >> 4] = B[(size_t)(bx * 64 + (idx >> 4)) * K + k0 + (idx & 15)];
    }
    __syncthreads();
#pragma unroll
    for (int kk = 0; kk < 16; ++kk) {
      float a[4], b[4];
#pragma unroll
      for (int i = 0; i < 4; ++i) a[i] = As[kk][ty * 4 + i];
#pragma unroll
      for (int j = 0; j < 4; ++j) b[j] = Bs[kk][tx * 4 + j];
#pragma unroll
      for (int i = 0; i < 4; ++i)
#pragma unroll
        for (int j = 0; j < 4; ++j) acc[i][j] += a[i] * b[j];
    }
    __syncthreads();
  }
#pragma unroll
  for (int i = 0; i < 4; ++i) {
    int gm = by * 64 + ty * 4 + i;
#pragma unroll
    for (int j = 0; j < 4; ++j) {
      int gn = bx * 64 + tx * 4 + j;
      float v = acc[i][j] + bias[gn];
      if (C)  C[(size_t)gm * N + gn] = v;
      if (Cb) Cb[(size_t)gm * N + gn] = f2bf(v);
    }
  }
}

// ---------------------------------------------------------------------------
// MFMA init GEMM, direct global->fragment loads (no LDS).
// out = feature(256x2048) @ W(1024x2048)^T + bias.  Grid (16, 4).
// ---------------------------------------------------------------------------
__global__ __launch_bounds__(256) void mfma_init_k(
    const u16* __restrict__ A, const u16* __restrict__ Bw,
    const float* __restrict__ bias, u16* __restrict__ outB, float* __restrict__ outF) {
  const int tid = threadIdx.x;
  const int m0 = blockIdx.y * 64, n0 = blockIdx.x * 64;
  const int l = tid & 63, wid = tid >> 6;
  const int wm = (wid & 1) * 32, wn = (wid >> 1) * 32;
  const int q = l >> 4, ln = l & 15;

  const u16* ar[2]; const u16* br[2];
#pragma unroll
  for (int i = 0; i < 2; ++i) {
    ar[i] = A + (size_t)(m0 + wm + i * 16 + ln) * FEAT_ + q * 8;
    br[i] = Bw + (size_t)(n0 + wn + i * 16 + ln) * FEAT_ + q * 8;
  }
  f32x4 acc[2][2];
  const f32x4 z = {0.f, 0.f, 0.f, 0.f};
  acc[0][0] = z; acc[0][1] = z; acc[1][0] = z; acc[1][1] = z;
#pragma unroll 2
  for (int kc = 0; kc < FEAT_; kc += 32) {
    bf16x8 a0 = *(const bf16x8_ma*)(ar[0] + kc);
    bf16x8 a1 = *(const bf16x8_ma*)(ar[1] + kc);
    bf16x8 b0 = *(const bf16x8_ma*)(br[0] + kc);
    bf16x8 b1 = *(const bf16x8_ma*)(br[1] + kc);
    acc[0][0] = __builtin_amdgcn_mfma_f32_16x16x32_bf16(a0, b0, acc[0][0], 0, 0, 0);
    acc[0][1] = __builtin_amdgcn_mfma_f32_16x16x32_bf16(a0, b1, acc[0][1], 0, 0, 0);
    acc[1][0] = __builtin_amdgcn_mfma_f32_16x16x32_bf16(a1, b0, acc[1][0], 0, 0, 0);
    acc[1][1] = __builtin_amdgcn_mfma_f32_16x16x32_bf16(a1, b1, acc[1][1], 0, 0, 0);
  }
#pragma unroll
  for (int i = 0; i < 2; ++i)
#pragma unroll
    for (int j = 0; j < 2; ++j)
#pragma unroll
      for (int r = 0; r < 4; ++r) {
        int row = m0 + wm + i * 16 + q * 4 + r;
        int col = n0 + wn + j * 16 + ln;
        float v = acc[i][j][r] + bias[col];
        if (outB) outB[(size_t)row * MEM_ + col] = f2bf(v);
        if (outF) outF[(size_t)row * MEM_ + col] = v;
      }
}

// ---------------------------------------------------------------------------
// Fused LSTM step, direct-load MFMA (no LDS staging, no K-loop barriers).
// 256 blocks x 256 thr; block -> 64 rows x 64 permuted gate-cols (16 units).
// ---------------------------------------------------------------------------
__global__ __launch_bounds__(256) void lstm_step_k(
    const u16* __restrict__ Xt, const u16* __restrict__ Hin,
    u16* __restrict__ Hout,
    const u16* __restrict__ WPih, const u16* __restrict__ WPhh,
    const float* __restrict__ biasP, float* __restrict__ c) {
  __shared__ __align__(16) float sG[64 * 68];
  const int tid = threadIdx.x;
  const int b = blockIdx.x;
  const int m0 = (b >> 6) * 64, nt = b & 63;
  const int l = tid & 63, wid = tid >> 6;
  const int wm = (wid & 1) * 32, wn = (wid >> 1) * 32;
  const int q = l >> 4, ln = l & 15;

  const u16* ax[2]; const u16* ah[2]; const u16* bi[2]; const u16* bh[2];
#pragma unroll
  for (int i = 0; i < 2; ++i) {
    int arow = m0 + wm + i * 16 + ln;
    int brow = nt * 64 + wn + i * 16 + ln;
    ax[i] = Xt + (size_t)arow * EMB_ + q * 8;
    ah[i] = Hin + (size_t)arow * MEM_ + q * 8;
    bi[i] = WPih + (size_t)brow * EMB_ + q * 8;
    bh[i] = WPhh + (size_t)brow * MEM_ + q * 8;
  }
  const float bj0 = biasP[nt * 64 + wn + ln];
  const float bj1 = biasP[nt * 64 + wn + 16 + ln];

  f32x4 acc[2][2];
  const f32x4 z = {0.f, 0.f, 0.f, 0.f};
  acc[0][0] = z; acc[0][1] = z; acc[1][0] = z; acc[1][1] = z;

  // phase 1: K over embedding (512)
#pragma unroll 2
  for (int kc = 0; kc < EMB_; kc += 32) {
    bf16x8 a0 = *(const bf16x8_ma*)(ax[0] + kc);
    bf16x8 a1 = *(const bf16x8_ma*)(ax[1] + kc);
    bf16x8 b0 = *(const bf16x8_ma*)(bi[0] + kc);
    bf16x8 b1 = *(const bf16x8_ma*)(bi[1] + kc);
    acc[0][0] = __builtin_amdgcn_mfma_f32_16x16x32_bf16(a0, b0, acc[0][0], 0, 0, 0);
    acc[0][1] = __builtin_amdgcn_mfma_f32_16x16x32_bf16(a0, b1, acc[0][1], 0, 0, 0);
    acc[1][0] = __builtin_amdgcn_mfma_f32_16x16x32_bf16(a1, b0, acc[1][0], 0, 0, 0);
    acc[1][1] = __builtin_amdgcn_mfma_f32_16x16x32_bf16(a1, b1, acc[1][1], 0, 0, 0);
  }
  // phase 2: K over hidden (1024)
#pragma unroll 2
  for (int kc = 0; kc < MEM_; kc += 32) {
    bf16x8 a0 = *(const bf16x8_ma*)(ah[0] + kc);
    bf16x8 a1 = *(const bf16x8_ma*)(ah[1] + kc);
    bf16x8 b0 = *(const bf16x8_ma*)(bh[0] + kc);
    bf16x8 b1 = *(const bf16x8_ma*)(bh[1] + kc);
    acc[0][0] = __builtin_amdgcn_mfma_f32_16x16x32_bf16(a0, b0, acc[0][0], 0, 0, 0);
    acc[0][1] = __builtin_amdgcn_mfma_f32_16x16x32_bf16(a0, b1, acc[0][1], 0, 0, 0);
    acc[1][0] = __builtin_amdgcn_mfma_f32_16x16x32_bf16(a1, b0, acc[1][0], 0, 0, 0);
    acc[1][1] = __builtin_amdgcn_mfma_f32_16x16x32_bf16(a1, b1, acc[1][1], 0, 0, 0);
  }

  // gate tile -> sG
#pragma unroll
  for (int i = 0; i < 2; ++i)
#pragma unroll
    for (int j = 0; j < 2; ++j)
#pragma unroll
      for (int r = 0; r < 4; ++r)
        sG[(wm + i * 16 + q * 4 + r) * 68 + wn + j * 16 + ln] =
            acc[i][j][r] + (j ? bj1 : bj0);
  __syncthreads();

  // pointwise: thread -> (row, 4 units); c in global fp32
  {
    const int prow = tid >> 2, u0 = (tid & 3) * 4;
    const float* gRow = sG + prow * 68 + u0 * 4;
    float* cp = c + (size_t)(m0 + prow) * MEM_ + nt * 16 + u0;
    float4 cv = *(const float4_ma*)cp;
    float cva[4] = {cv.x, cv.y, cv.z, cv.w};
    u16x4 hv;
    float cna[4];
#pragma unroll
    for (int k = 0; k < 4; ++k) {
      float4 g4 = *(const float4_ma*)(gRow + k * 4);   // (i,f,g,o)
      float cvn = sigmoidf_(g4.y) * cva[k] + sigmoidf_(g4.x) * tanhf_(g4.z);
      cna[k] = cvn;
      hv[k] = f2bf(sigmoidf_(g4.w) * tanhf_(cvn));
    }
    float4 cn = {cna[0], cna[1], cna[2], cna[3]};
    *(float4_ma*)cp = cn;
    *(u16x4_ma*)(Hout + (size_t)(m0 + prow) * MEM_ + nt * 16 + u0) = hv;
  }
}

// ---------------------------------------------------------------------------
// Logits GEMM + fused sum-exp partials, direct-load MFMA (no LDS staging).
// Tile 128x128, 4 waves (each 64x64).  1D grid, vt-major.
// ---------------------------------------------------------------------------
__global__ __launch_bounds__(256) void mfma_logits_k(
    const u16* __restrict__ H, const u16* __restrict__ WoutB,
    const float* __restrict__ bout, const int* __restrict__ caption,
    float* __restrict__ psum, float* __restrict__ tlog) {
  __shared__ __align__(16) float eS[256];
  __shared__ __align__(16) float eT[256];
  const int tid = threadIdx.x;
  const int bid = blockIdx.x;
  const int vt = bid / 62, mt = bid - vt * 62;
  const int n0 = vt * VT_, m0 = mt * 128;
  const int l = tid & 63, wid = tid >> 6;
  const int wm = (wid & 1) * 64, wn = (wid >> 1) * 64;
  const int q = l >> 4, ln = l & 15;

  const u16* ar[4]; const u16* br[4];
  int colj[4];
#pragma unroll
  for (int i = 0; i < 4; ++i) {
    ar[i] = H + (size_t)(m0 + wm + i * 16 + ln) * MEM_ + q * 8;
    colj[i] = n0 + wn + i * 16 + ln;
    int brow = (colj[i] > VOCAB_ - 1) ? (VOCAB_ - 1) : colj[i];
    br[i] = WoutB + (size_t)brow * MEM_ + q * 8;
  }

  f32x4 acc[4][4];
  const f32x4 z = {0.f, 0.f, 0.f, 0.f};
#pragma unroll
  for (int i = 0; i < 4; ++i)
#pragma unroll
    for (int j = 0; j < 4; ++j) acc[i][j] = z;

#pragma unroll 2
  for (int kc = 0; kc < MEM_; kc += 32) {
    bf16x8 a[4], b[4];
#pragma unroll
    for (int i = 0; i < 4; ++i) a[i] = *(const bf16x8_ma*)(ar[i] + kc);
#pragma unroll
    for (int j = 0; j < 4; ++j) b[j] = *(const bf16x8_ma*)(br[j] + kc);
#pragma unroll
    for (int i = 0; i < 4; ++i)
#pragma unroll
      for (int j = 0; j < 4; ++j)
        acc[i][j] = __builtin_amdgcn_mfma_f32_16x16x32_bf16(a[i], b[j], acc[i][j], 0, 0, 0);
  }

  // ---- fused sum-exp epilogue ----
  const int half = wid >> 1;
  float bj[4];
#pragma unroll
  for (int j = 0; j < 4; ++j) bj[j] = (colj[j] < VOCAB_) ? bout[colj[j]] : 0.f;
#pragma unroll
  for (int i = 0; i < 4; ++i) {
#pragma unroll
    for (int r = 0; r < 4; ++r) {
      const int rloc = wm + i * 16 + q * 4 + r;
      const int trow = m0 + rloc;
      const int tgt = caption[(trow & 255) * TT_ + (trow >> 8) + 1];
      float s = 0.f, tv = 0.f;
#pragma unroll
      for (int j = 0; j < 4; ++j) {
        if (colj[j] < VOCAB_) {
          float v = acc[i][j][r] + bj[j];
          s += __expf(v);
          if (colj[j] == tgt) tv += v;
        }
      }
      s = redsum16(s);
      tv = redsum16(tv);
      if (ln == 0) {
        eS[rloc * 2 + half] = s;
        eT[rloc * 2 + half] = tv;
      }
    }
  }
  __syncthreads();
  if (tid < 128) {
    int trow = m0 + tid;
    psum[(size_t)trow * NTV_ + vt] = eS[tid * 2] + eS[tid * 2 + 1];
    int tgt = caption[(trow & 255) * TT_ + (trow >> 8) + 1];
    if (tgt >= n0 && tgt < n0 + VT_) tlog[trow] = eT[tid * 2] + eT[tid * 2 + 1];
  }
}

// ---------------------------------------------------------------------------
// Fallback logits (fp32 W_out staged inline through LDS) — only if ws small.
// ---------------------------------------------------------------------------
__global__ __launch_bounds__(256) void mfma_logits_conv_k(
    const u16* __restrict__ H, const float* __restrict__ WoutF,
    const float* __restrict__ bout, const int* __restrict__ caption,
    float* __restrict__ psum, float* __restrict__ tlog) {
  __shared__ __align__(16) char smem[16384];
  u16* sA = (u16*)smem;
  u16* sB = (u16*)(smem + 8192);
  const int tid = threadIdx.x;
  const int bid = blockIdx.x;
  const int vt = bid / 62, mt = bid - vt * 62;
  const int n0 = vt * VT_, m0 = mt * 128;
  const int l = tid & 63, wid = tid >> 6;
  const int wm = (wid & 1) * 64, wn = (wid >> 1) * 64;
  const int q = l >> 4, ln = l & 15;
  f32x4 acc[4][4];
  const f32x4 z = {0.f, 0.f, 0.f, 0.f};
#pragma unroll
  for (int i = 0; i < 4; ++i)
#pragma unroll
    for (int j = 0; j < 4; ++j) acc[i][j] = z;
  const int srow = tid >> 2, scol = (tid & 3) * 8;
  int brow[2];
#pragma unroll
  for (int r = 0; r < 2; ++r) {
    int gr = n0 + srow + r * 64;
    brow[r] = (gr > VOCAB_ - 1) ? (VOCAB_ - 1) : gr;
  }
  for (int k0 = 0; k0 < MEM_; k0 += 32) {
#pragma unroll
    for (int r = 0; r < 2; ++r)
      async16(H + (size_t)(m0 + srow + r * 64) * MEM_ + k0 + scol,
              sA + (srow + r * 64) * 32 + scol);
#pragma unroll
    for (int r = 0; r < 2; ++r) {
      const float* g = WoutF + (size_t)brow[r] * MEM_ + k0 + scol;
      float4 v0 = *(const float4_ma*)g;
      float4 v1 = *(const float4_ma*)(g + 4);
      u16x8 o = { f2bf(v0.x), f2bf(v0.y), f2bf(v0.z), f2bf(v0.w),
                  f2bf(v1.x), f2bf(v1.y), f2bf(v1.z), f2bf(v1.w) };
      *(u16x8_ma*)(sB + (srow + r * 64) * 32 + scol) = o;
    }
    __syncthreads();
    bf16x8 a[4], b[4];
#pragma unroll
    for (int i = 0; i < 4; ++i) a[i] = *(const bf16x8_ma*)(sA + (wm + i * 16 + ln) * 32 + q * 8);
#pragma unroll
    for (int j = 0; j < 4; ++j) b[j] = *(const bf16x8_ma*)(sB + (wn + j * 16 + ln) * 32 + q * 8);
#pragma unroll
    for (int i = 0; i < 4; ++i)
#pragma unroll
      for (int j = 0; j < 4; ++j)
        acc[i][j] = __builtin_amdgcn_mfma_f32_16x16x32_bf16(a[i], b[j], acc[i][j], 0, 0, 0);
    __syncthreads();
  }
  float* eS = (float*)smem;
  float* eT = eS + 256;
  const int half = wid >> 1;
  int colj[4]; float bj[4];
#pragma unroll
  for (int j = 0; j < 4; ++j) {
    colj[j] = n0 + wn + j * 16 + ln;
    bj[j] = (colj[j] < VOCAB_) ? bout[colj[j]] : 0.f;
  }
#pragma unroll
  for (int i = 0; i < 4; ++i) {
#pragma unroll
    for (int r = 0; r < 4; ++r) {
      const int rloc = wm + i * 16 + q * 4 + r;
      const int trow = m0 + rloc;
      const int tgt = caption[(trow & 255) * TT_ + (trow >> 8) + 1];
      float s = 0.f, tv = 0.f;
#pragma unroll
      for (int j = 0; j < 4; ++j) {
        if (colj[j] < VOCAB_) {
          float v = acc[i][j][r] + bj[j];
          s += __expf(v);
          if (colj[j] == tgt) tv += v;
        }
      }
      s = redsum16(s);
      tv = redsum16(tv);
      if (ln == 0) { eS[rloc * 2 + half] = s; eT[rloc * 2 + half] = tv; }
    }
  }
  __syncthreads();
  if (tid < 128) {
    int trow = m0 + tid;
    psum[(size_t)trow * NTV_ + vt] = eS[tid * 2] + eS[tid * 2 + 1];
    int tgt = caption[(trow & 255) * TT_ + (trow >> 8) + 1];
    if (tgt >= n0 && tgt < n0 + VT_) tlog[trow] = eT[tid * 2] + eT[tid * 2 + 1];
  }
}

// ---------------------------------------------------------------------------
__global__ __launch_bounds__(256) void combine_k(
    const float* __restrict__ psum, const float* __restrict__ tlog,
    const int* __restrict__ caption, float* __restrict__ accum) {
  int r = blockIdx.x * 256 + threadIdx.x;
  if (r >= MROWS_) return;
  const float* ps = psum + (size_t)r * NTV_;
  float s = 0.f;
  for (int j = 0; j < NTV_; ++j) s += ps[j];
  float nll = __logf(s) - tlog[r];
  int tgt = caption[(r & 255) * TT_ + (r >> 8) + 1];
  if (tgt != 0) {
    atomicAdd(&accum[0], nll);
    atomicAdd(&accum[1], 1.f);
  }
}

__global__ void zero_words_k(unsigned* buf) {
  buf[threadIdx.x] = 0u;
}

__global__ void finalize_k(const float* __restrict__ accum, float* __restrict__ out) {
  out[0] = accum[0] / fmaxf(accum[1], 1.0f);
}

// ---------------------------------------------------------------------------
extern "C" void kernel_launch(void* const* d_in, const int* in_sizes, int n_in,
                              void* d_out, int out_size, void* d_ws, size_t ws_size,
                              hipStream_t stream) {
  (void)in_sizes; (void)n_in; (void)out_size;
  const float* feature  = (const float*)d_in[0];
  const int*   caption  = (const int*)d_in[1];
  const float* W_init_h = (const float*)d_in[3];
  const float* b_init_h = (const float*)d_in[4];
  const float* W_init_c = (const float*)d_in[5];
  const float* b_init_c = (const float*)d_in[6];
  const float* emb      = (const float*)d_in[7];
  const float* W_ih     = (const float*)d_in[8];
  const float* b_ih     = (const float*)d_in[9];
  const float* W_hh     = (const float*)d_in[10];
  const float* b_hh     = (const float*)d_in[11];
  const float* W_out    = (const float*)d_in[12];
  const float* b_out    = (const float*)d_in[13];
  float* out = (float*)d_out;

  char* p = (char*)d_ws;
  u16* WPih = (u16*)p;       p += (size_t)4096 * 512 * 2;
  u16* WPhh = (u16*)p;       p += (size_t)4096 * 1024 * 2;
  float* biasP = (float*)p;  p += (size_t)4096 * 4;
  u16* Xall = (u16*)p;       p += (size_t)NSTEP * 256 * 512 * 2;
  u16* Hall = (u16*)p;       p += (size_t)32 * 256 * 1024 * 2;
  float* c0 = (float*)p;     p += (size_t)256 * 1024 * 4;
  float* psum = (float*)p;   p += (size_t)MROWS_ * NTV_ * 4;
  float* tlog = (float*)p;   p += (size_t)MROWS_ * 4;
  unsigned* syncbuf = (unsigned*)p; p += 256;
  u16* WoutB = (u16*)p;      p += (size_t)VOCAB_ * 1024 * 2;
  size_t woutEnd = (size_t)(p - (char*)d_ws);
  u16* featB = (u16*)p;      p += (size_t)256 * 2048 * 2;
  u16* WinitHB = (u16*)p;    p += (size_t)1024 * 2048 * 2;
  u16* WinitCB = (u16*)p;    p += (size_t)1024 * 2048 * 2;
  size_t initEnd = (size_t)(p - (char*)d_ws);

  bool haveWoutB = (ws_size >= woutEnd);
  bool haveInitB = (ws_size >= initEnd);

  float* accum = (float*)syncbuf;

  dim3 blk(256);
  zero_words_k<<<1, 64, 0, stream>>>(syncbuf);
  cvt_permute_k<<<4096, 128, 0, stream>>>(W_ih, W_hh, b_ih, b_hh, WPih, WPhh, biasP);
  gather_x_k<<<3968, blk, 0, stream>>>(emb, caption, Xall);
  if (haveWoutB) cvt_bf16_k<<<10000, blk, 0, stream>>>(W_out, WoutB, 2560000);

  if (haveInitB) {
    cvt_bf16_k<<<512, blk, 0, stream>>>(feature, featB, 131072);
    cvt_bf16_k<<<2048, blk, 0, stream>>>(W_init_h, WinitHB, 524288);
    cvt_bf16_k<<<2048, blk, 0, stream>>>(W_init_c, WinitCB, 524288);
    dim3 gi(16, 4);
    mfma_init_k<<<gi, blk, 0, stream>>>(featB, WinitHB, b_init_h, Hall, nullptr);
    mfma_init_k<<<gi, blk, 0, stream>>>(featB, WinitCB, b_init_c, nullptr, c0);
  } else {
    dim3 gi(16, 4);
    gemm_nt_bias_k<<<gi, blk, 0, stream>>>(feature, W_init_h, b_init_h, nullptr, Hall,
                                           BS_, MEM_, FEAT_);
    gemm_nt_bias_k<<<gi, blk, 0, stream>>>(feature, W_init_c, b_init_c, c0, nullptr,
                                           BS_, MEM_, FEAT_);
  }

  for (int t = 0; t < NSTEP; ++t) {
    lstm_step_k<<<256, blk, 0, stream>>>(Xall + (size_t)t * BS_ * EMB_,
                                         Hall + (size_t)t * BS_ * MEM_,
                                         Hall + (size_t)(t + 1) * BS_ * MEM_,
                                         WPih, WPhh, biasP, c0);
  }

  if (haveWoutB)
    mfma_logits_k<<<NTV_ * 62, blk, 0, stream>>>(Hall + (size_t)BS_ * MEM_, WoutB,
                                                 b_out, caption, psum, tlog);
  else
    mfma_logits_conv_k<<<NTV_ * 62, blk, 0, stream>>>(Hall + (size_t)BS_ * MEM_, W_out,
                                                      b_out, caption, psum, tlog);

  combine_k<<<31, blk, 0, stream>>>(psum, tlog, caption, accum);
  finalize_k<<<1, 1, 0, stream>>>(accum, out);
}

// Round 6
// 770.650 us; speedup vs baseline: 2.2265x; 2.2265x over previous
//
#include <hip/hip_runtime.h>
#include <math.h>

#define BS_    256
#define FEAT_  2048
#define EMB_   512
#define MEM_   1024
#define VOCAB_ 10000
#define TT_    32
#define NSTEP  31
#define VT_    128
#define NTV_   79      // ceil(10000/128)
#define MROWS_ 7936    // 31*256
#define PAD_   40      // logits/init LDS row stride (bf16 elems)
#define SP_    80      // step LDS row stride (bf16 elems): 160B, 2-way banks free

typedef unsigned short u16;
typedef __bf16 bf16x8 __attribute__((ext_vector_type(8)));
typedef float  f32x4  __attribute__((ext_vector_type(4)));
typedef u16    u16x8  __attribute__((ext_vector_type(8)));
typedef u16    u16x4  __attribute__((ext_vector_type(4)));
typedef bf16x8 __attribute__((may_alias)) bf16x8_ma;
typedef u16x8  __attribute__((may_alias)) u16x8_ma;
typedef u16x4  __attribute__((may_alias)) u16x4_ma;
typedef float4 __attribute__((may_alias)) float4_ma;

__device__ __forceinline__ u16 f2bf(float f) {
  unsigned u = __float_as_uint(f);
  u += 0x7FFFu + ((u >> 16) & 1u);
  return (u16)(u >> 16);
}

__device__ __forceinline__ void async16(const void* g, void* s) {
  __builtin_amdgcn_global_load_lds((const __attribute__((address_space(1))) void*)g,
                                   (__attribute__((address_space(3))) void*)s, 16, 0, 0);
}

__device__ __forceinline__ float redsum16(float v) {
#pragma unroll
  for (int m = 1; m < 16; m <<= 1) v += __shfl_xor(v, m, 64);
  return v;
}
__device__ __forceinline__ float sigmoidf_(float x) { return 1.0f / (1.0f + __expf(-x)); }
__device__ __forceinline__ float tanhf_(float x) {
  float e = __expf(2.0f * x);
  return 1.0f - 2.0f / (e + 1.0f);
}

// ---------------------------------------------------------------------------
__global__ __launch_bounds__(256) void cvt_bf16_k(const float* __restrict__ in,
                                                  u16* __restrict__ out, int n4) {
  int i = blockIdx.x * 256 + threadIdx.x;
  if (i >= n4) return;
  float4 v = ((const float4_ma*)in)[i];
  u16x4 o = { f2bf(v.x), f2bf(v.y), f2bf(v.z), f2bf(v.w) };
  *(u16x4_ma*)(out + (size_t)i * 4) = o;
}

// ---------------------------------------------------------------------------
// Gate-permuted weights: permuted row r -> source row (r&3)*1024+(r>>2)
// ---------------------------------------------------------------------------
__global__ __launch_bounds__(128) void cvt_permute_k(
    const float* __restrict__ W_ih, const float* __restrict__ W_hh,
    const float* __restrict__ b_ih, const float* __restrict__ b_hh,
    u16* __restrict__ WPih, u16* __restrict__ WPhh, float* __restrict__ biasP) {
  int r = blockIdx.x, tid = threadIdx.x;
  int u = r >> 2, g = r & 3, s = g * 1024 + u;
  {
    float4 v = *(const float4_ma*)(W_ih + (size_t)s * EMB_ + tid * 4);
    u16x4 o = { f2bf(v.x), f2bf(v.y), f2bf(v.z), f2bf(v.w) };
    *(u16x4_ma*)(WPih + (size_t)r * EMB_ + tid * 4) = o;
  }
#pragma unroll
  for (int h = 0; h < 2; ++h) {
    int idx = h * 512 + tid * 4;
    float4 v = *(const float4_ma*)(W_hh + (size_t)s * MEM_ + idx);
    u16x4 o = { f2bf(v.x), f2bf(v.y), f2bf(v.z), f2bf(v.w) };
    *(u16x4_ma*)(WPhh + (size_t)r * MEM_ + idx) = o;
  }
  if (tid == 0) biasP[r] = b_ih[s] + b_hh[s];
}

// ---------------------------------------------------------------------------
__global__ __launch_bounds__(256) void gather_x_k(const float* __restrict__ emb,
                                                  const int* __restrict__ caption,
                                                  u16* __restrict__ X) {
  int i = blockIdx.x * 256 + threadIdx.x;
  int e4 = (i & 127) * 4;
  int b  = (i >> 7) & 255;
  int t  = i >> 15;
  int cap = caption[b * TT_ + t];
  float4 v = *(const float4_ma*)(emb + (size_t)cap * EMB_ + e4);
  u16x4 o = { f2bf(v.x), f2bf(v.y), f2bf(v.z), f2bf(v.w) };
  *(u16x4_ma*)(X + ((size_t)(t * 256 + b) * EMB_ + e4)) = o;
}

// ---------------------------------------------------------------------------
// fp32 vector GEMM fallback for init
// ---------------------------------------------------------------------------
__global__ __launch_bounds__(256) void gemm_nt_bias_k(
    const float* __restrict__ A, const float* __restrict__ B,
    const float* __restrict__ bias, float* __restrict__ C, u16* __restrict__ Cb,
    int M, int N, int K) {
  __shared__ float As[16][65];
  __shared__ float Bs[16][65];
  int tid = threadIdx.x;
  int bx = blockIdx.x, by = blockIdx.y;
  int tx = tid & 15, ty = tid >> 4;
  float acc[4][4] = {};
  for (int k0 = 0; k0 < K; k0 += 16) {
#pragma unroll
    for (int i = 0; i < 4; ++i) {
      int idx = tid + i * 256;
      As[idx & 15][idx >> 4] = A[(size_t)(by * 64 + (idx >> 4)) * K + k0 + (idx & 15)];
    }
#pragma unroll
    for (int i = 0; i < 4; ++i) {
      int idx = tid + i * 256;
      Bs[idx & 15][idx >> 4] = B[(size_t)(bx * 64 + (idx >> 4)) * K + k0 + (idx & 15)];
    }
    __syncthreads();
#pragma unroll
    for (int kk = 0; kk < 16; ++kk) {
      float a[4], b[4];
#pragma unroll
      for (int i = 0; i < 4; ++i) a[i] = As[kk][ty * 4 + i];
#pragma unroll
      for (int j = 0; j < 4; ++j) b[j] = Bs[kk][tx * 4 + j];
#pragma unroll
      for (int i = 0; i < 4; ++i)
#pragma unroll
        for (int j = 0; j < 4; ++j) acc[i][j] += a[i] * b[j];
    }
    __syncthreads();
  }
#pragma unroll
  for (int i = 0; i < 4; ++i) {
    int gm = by * 64 + ty * 4 + i;
#pragma unroll
    for (int j = 0; j < 4; ++j) {
      int gn = bx * 64 + tx * 4 + j;
      float v = acc[i][j] + bias[gn];
      if (C)  C[(size_t)gm * N + gn] = v;
      if (Cb) Cb[(size_t)gm * N + gn] = f2bf(v);
    }
  }
}

// ---------------------------------------------------------------------------
// MFMA init GEMM (r4 version): 64x64 tile, dbuf reg-prefetch.  Grid (16, 4).
// ---------------------------------------------------------------------------
__global__ __launch_bounds__(256) void mfma_init_k(
    const u16* __restrict__ A, const u16* __restrict__ Bw,
    const float* __restrict__ bias, u16* __restrict__ outB, float* __restrict__ outF) {
  __shared__ __align__(16) u16 sA[2][64 * PAD_];
  __shared__ __align__(16) u16 sB[2][64 * PAD_];
  const int tid = threadIdx.x;
  const int m0 = blockIdx.y * 64, n0 = blockIdx.x * 64;
  const int l = tid & 63, wid = tid >> 6;
  const int wm = (wid & 1) * 32, wn = (wid >> 1) * 32;
  const int q = l >> 4, ln = l & 15;
  const int srow = tid >> 2, scol = (tid & 3) * 8;
  const u16* Ar = A + (size_t)(m0 + srow) * FEAT_ + scol;
  const u16* Br = Bw + (size_t)(n0 + srow) * FEAT_ + scol;

  f32x4 acc[2][2];
  const f32x4 z = {0.f, 0.f, 0.f, 0.f};
  acc[0][0] = z; acc[0][1] = z; acc[1][0] = z; acc[1][1] = z;

  u16x8 ra = *(const u16x8_ma*)Ar;
  u16x8 rb = *(const u16x8_ma*)Br;
  int p = 0;
  for (int it = 0; it < FEAT_ / 32; ++it) {
    *(u16x8_ma*)(sA[p] + srow * PAD_ + scol) = ra;
    *(u16x8_ma*)(sB[p] + srow * PAD_ + scol) = rb;
    __syncthreads();
    if (it + 1 < FEAT_ / 32) {
      ra = *(const u16x8_ma*)(Ar + (it + 1) * 32);
      rb = *(const u16x8_ma*)(Br + (it + 1) * 32);
    }
    bf16x8 a0 = *(const bf16x8_ma*)(sA[p] + (wm + ln) * PAD_ + q * 8);
    bf16x8 a1 = *(const bf16x8_ma*)(sA[p] + (wm + 16 + ln) * PAD_ + q * 8);
    bf16x8 b0 = *(const bf16x8_ma*)(sB[p] + (wn + ln) * PAD_ + q * 8);
    bf16x8 b1 = *(const bf16x8_ma*)(sB[p] + (wn + 16 + ln) * PAD_ + q * 8);
    acc[0][0] = __builtin_amdgcn_mfma_f32_16x16x32_bf16(a0, b0, acc[0][0], 0, 0, 0);
    acc[0][1] = __builtin_amdgcn_mfma_f32_16x16x32_bf16(a0, b1, acc[0][1], 0, 0, 0);
    acc[1][0] = __builtin_amdgcn_mfma_f32_16x16x32_bf16(a1, b0, acc[1][0], 0, 0, 0);
    acc[1][1] = __builtin_amdgcn_mfma_f32_16x16x32_bf16(a1, b1, acc[1][1], 0, 0, 0);
    p ^= 1;
  }
#pragma unroll
  for (int i = 0; i < 2; ++i)
#pragma unroll
    for (int j = 0; j < 2; ++j)
#pragma unroll
      for (int r = 0; r < 4; ++r) {
        int row = m0 + wm + i * 16 + q * 4 + r;
        int col = n0 + wn + j * 16 + ln;
        float v = acc[i][j][r] + bias[col];
        if (outB) outB[(size_t)row * MEM_ + col] = f2bf(v);
        if (outF) outF[(size_t)row * MEM_ + col] = v;
      }
}

// ---------------------------------------------------------------------------
// Fused LSTM step: BK=64 (24 iters), prefetch depth 2, LDS stride 80.
// 256 blocks x 256 thr; block -> 64 rows x 64 permuted gate-cols.
// ---------------------------------------------------------------------------
__global__ __launch_bounds__(256) void lstm_step_k(
    const u16* __restrict__ Xt, const u16* __restrict__ Hin,
    u16* __restrict__ Hout,
    const u16* __restrict__ WPih, const u16* __restrict__ WPhh,
    const float* __restrict__ biasP, float* __restrict__ c) {
  __shared__ __align__(16) u16 sA[2][64 * SP_];
  __shared__ __align__(16) u16 sB[2][64 * SP_];
  __shared__ __align__(16) float sG[64 * 68];
  const int tid = threadIdx.x;
  const int b = blockIdx.x;
  const int m0 = (b >> 6) * 64, nt = b & 63;
  const int l = tid & 63, wid = tid >> 6;
  const int wm = (wid & 1) * 32, wn = (wid >> 1) * 32;
  const int q = l >> 4, ln = l & 15;
  const int srow = tid >> 2, scol = (tid & 3) * 8;

  const u16* aX = Xt  + (size_t)(m0 + srow) * EMB_ + scol;
  const u16* aH = Hin + (size_t)(m0 + srow) * MEM_ + scol;
  const u16* bX = WPih + (size_t)(nt * 64 + srow) * EMB_ + scol;
  const u16* bH = WPhh + (size_t)(nt * 64 + srow) * MEM_ + scol;

  const float bj0 = biasP[nt * 64 + wn + ln];
  const float bj1 = biasP[nt * 64 + wn + 16 + ln];

  f32x4 acc[2][2];
  const f32x4 z = {0.f, 0.f, 0.f, 0.f};
  acc[0][0] = z; acc[0][1] = z; acc[1][0] = z; acc[1][1] = z;

  // depth-2 register prefetch: set s holds data for iteration it with it&1==s
  u16x8 rA[2][2], rB[2][2];
#pragma unroll
  for (int s = 0; s < 2; ++s)
#pragma unroll
    for (int cc = 0; cc < 2; ++cc) {
      int k = s * 64 + cc * 32;   // < 512: embedding region
      rA[s][cc] = *(const u16x8_ma*)(aX + k);
      rB[s][cc] = *(const u16x8_ma*)(bX + k);
    }

  for (int it = 0; it < 24; ++it) {
    const int s = it & 1;
#pragma unroll
    for (int cc = 0; cc < 2; ++cc) {
      *(u16x8_ma*)(sA[s] + srow * SP_ + scol + 32 * cc) = rA[s][cc];
      *(u16x8_ma*)(sB[s] + srow * SP_ + scol + 32 * cc) = rB[s][cc];
    }
    __syncthreads();
    if (it + 2 < 24) {
#pragma unroll
      for (int cc = 0; cc < 2; ++cc) {
        int k = (it + 2) * 64 + cc * 32;
        if (k < EMB_) {
          rA[s][cc] = *(const u16x8_ma*)(aX + k);
          rB[s][cc] = *(const u16x8_ma*)(bX + k);
        } else {
          rA[s][cc] = *(const u16x8_ma*)(aH + (k - EMB_));
          rB[s][cc] = *(const u16x8_ma*)(bH + (k - EMB_));
        }
      }
    }
#pragma unroll
    for (int kk = 0; kk < 2; ++kk) {
      bf16x8 a0 = *(const bf16x8_ma*)(sA[s] + (wm + ln) * SP_ + kk * 32 + q * 8);
      bf16x8 a1 = *(const bf16x8_ma*)(sA[s] + (wm + 16 + ln) * SP_ + kk * 32 + q * 8);
      bf16x8 b0 = *(const bf16x8_ma*)(sB[s] + (wn + ln) * SP_ + kk * 32 + q * 8);
      bf16x8 b1 = *(const bf16x8_ma*)(sB[s] + (wn + 16 + ln) * SP_ + kk * 32 + q * 8);
      acc[0][0] = __builtin_amdgcn_mfma_f32_16x16x32_bf16(a0, b0, acc[0][0], 0, 0, 0);
      acc[0][1] = __builtin_amdgcn_mfma_f32_16x16x32_bf16(a0, b1, acc[0][1], 0, 0, 0);
      acc[1][0] = __builtin_amdgcn_mfma_f32_16x16x32_bf16(a1, b0, acc[1][0], 0, 0, 0);
      acc[1][1] = __builtin_amdgcn_mfma_f32_16x16x32_bf16(a1, b1, acc[1][1], 0, 0, 0);
    }
  }

  // gate tile -> sG
#pragma unroll
  for (int i = 0; i < 2; ++i)
#pragma unroll
    for (int j = 0; j < 2; ++j)
#pragma unroll
      for (int r = 0; r < 4; ++r)
        sG[(wm + i * 16 + q * 4 + r) * 68 + wn + j * 16 + ln] =
            acc[i][j][r] + (j ? bj1 : bj0);
  __syncthreads();

  // pointwise: thread -> (row, 4 units); c in global fp32
  {
    const int prow = tid >> 2, u0 = (tid & 3) * 4;
    const float* gRow = sG + prow * 68 + u0 * 4;
    float* cp = c + (size_t)(m0 + prow) * MEM_ + nt * 16 + u0;
    float4 cv = *(const float4_ma*)cp;
    float cva[4] = {cv.x, cv.y, cv.z, cv.w};
    u16x4 hv;
    float cna[4];
#pragma unroll
    for (int k = 0; k < 4; ++k) {
      float4 g4 = *(const float4_ma*)(gRow + k * 4);   // (i,f,g,o)
      float cvn = sigmoidf_(g4.y) * cva[k] + sigmoidf_(g4.x) * tanhf_(g4.z);
      cna[k] = cvn;
      hv[k] = f2bf(sigmoidf_(g4.w) * tanhf_(cvn));
    }
    float4 cn = {cna[0], cna[1], cna[2], cna[3]};
    *(float4_ma*)cp = cn;
    *(u16x4_ma*)(Hout + (size_t)(m0 + prow) * MEM_ + nt * 16 + u0) = hv;
  }
}

// ---------------------------------------------------------------------------
// Logits GEMM + fused sum-exp partials (r4 body) with XCD-banded decode:
// xcd = bid&7 owns m-tiles [xcd*8, xcd*8+8); vt sweeps slowly -> per-XCD H
// band (2 MB) stays L2-resident, Wout streams through L3.
// Grid: 8 * 632 = 5056 blocks.
// ---------------------------------------------------------------------------
__device__ __forceinline__ void logits_decode(int bid, int& vt, int& mt) {
  int xcd = bid & 7, s = bid >> 3;
  vt = s >> 3;
  mt = xcd * 8 + (s & 7);
}

__global__ __launch_bounds__(256) void mfma_logits_k(
    const u16* __restrict__ H, const u16* __restrict__ WoutB,
    const float* __restrict__ bout, const int* __restrict__ caption,
    float* __restrict__ psum, float* __restrict__ tlog) {
  __shared__ __align__(16) u16 sA[2][128 * PAD_];
  __shared__ __align__(16) u16 sB[2][128 * PAD_];
  const int tid = threadIdx.x;
  int vt, mt;
  logits_decode(blockIdx.x, vt, mt);
  if (mt >= 62) return;
  const int n0 = vt * VT_, m0 = mt * 128;
  const int l = tid & 63, wid = tid >> 6;
  const int wm = (wid & 1) * 64, wn = (wid >> 1) * 64;
  const int q = l >> 4, ln = l & 15;

  f32x4 acc[4][4];
  const f32x4 z = {0.f, 0.f, 0.f, 0.f};
#pragma unroll
  for (int i = 0; i < 4; ++i)
#pragma unroll
    for (int j = 0; j < 4; ++j) acc[i][j] = z;

  int arow[2], acol[2], brow[2];
#pragma unroll
  for (int r = 0; r < 2; ++r) {
    int idx = tid + r * 256;
    arow[r] = idx >> 2;
    acol[r] = (idx & 3) * 8;
    int gr = n0 + arow[r];
    brow[r] = (gr > VOCAB_ - 1) ? (VOCAB_ - 1) : gr;
  }

  u16x8 ra[2], rb[2];
#pragma unroll
  for (int r = 0; r < 2; ++r) {
    ra[r] = *(const u16x8_ma*)(H + (size_t)(m0 + arow[r]) * MEM_ + acol[r]);
    rb[r] = *(const u16x8_ma*)(WoutB + (size_t)brow[r] * MEM_ + acol[r]);
  }
  int p = 0;
  for (int it = 0; it < 32; ++it) {
#pragma unroll
    for (int r = 0; r < 2; ++r) {
      *(u16x8_ma*)(sA[p] + arow[r] * PAD_ + acol[r]) = ra[r];
      *(u16x8_ma*)(sB[p] + arow[r] * PAD_ + acol[r]) = rb[r];
    }
    __syncthreads();
    if (it + 1 < 32) {
      int k0 = (it + 1) * 32;
#pragma unroll
      for (int r = 0; r < 2; ++r) {
        ra[r] = *(const u16x8_ma*)(H + (size_t)(m0 + arow[r]) * MEM_ + k0 + acol[r]);
        rb[r] = *(const u16x8_ma*)(WoutB + (size_t)brow[r] * MEM_ + k0 + acol[r]);
      }
    }
    bf16x8 a[4], b[4];
#pragma unroll
    for (int i = 0; i < 4; ++i) a[i] = *(const bf16x8_ma*)(sA[p] + (wm + i * 16 + ln) * PAD_ + q * 8);
#pragma unroll
    for (int j = 0; j < 4; ++j) b[j] = *(const bf16x8_ma*)(sB[p] + (wn + j * 16 + ln) * PAD_ + q * 8);
#pragma unroll
    for (int i = 0; i < 4; ++i)
#pragma unroll
      for (int j = 0; j < 4; ++j)
        acc[i][j] = __builtin_amdgcn_mfma_f32_16x16x32_bf16(a[i], b[j], acc[i][j], 0, 0, 0);
    __syncthreads();
    p ^= 1;
  }

  // ---- fused sum-exp epilogue (reuse sA as float scratch) ----
  float* eS = (float*)sA;          // [128][2]
  float* eT = eS + 256;
  const int half = wid >> 1;

  int colj[4]; float bj[4];
#pragma unroll
  for (int j = 0; j < 4; ++j) {
    colj[j] = n0 + wn + j * 16 + ln;
    bj[j] = (colj[j] < VOCAB_) ? bout[colj[j]] : 0.f;
  }
#pragma unroll
  for (int i = 0; i < 4; ++i) {
#pragma unroll
    for (int r = 0; r < 4; ++r) {
      const int rloc = wm + i * 16 + q * 4 + r;
      const int trow = m0 + rloc;
      const int tgt = caption[(trow & 255) * TT_ + (trow >> 8) + 1];
      float s = 0.f, tv = 0.f;
#pragma unroll
      for (int j = 0; j < 4; ++j) {
        if (colj[j] < VOCAB_) {
          float v = acc[i][j][r] + bj[j];
          s += __expf(v);
          if (colj[j] == tgt) tv += v;
        }
      }
      s = redsum16(s);
      tv = redsum16(tv);
      if (ln == 0) {
        eS[rloc * 2 + half] = s;
        eT[rloc * 2 + half] = tv;
      }
    }
  }
  __syncthreads();
  if (tid < 128) {
    int trow = m0 + tid;
    psum[(size_t)trow * NTV_ + vt] = eS[tid * 2] + eS[tid * 2 + 1];
    int tgt = caption[(trow & 255) * TT_ + (trow >> 8) + 1];
    if (tgt >= n0 && tgt < n0 + VT_) tlog[trow] = eT[tid * 2] + eT[tid * 2 + 1];
  }
}

// ---------------------------------------------------------------------------
// Fallback logits (fp32 W_out staged inline through LDS) — only if ws small.
// ---------------------------------------------------------------------------
__global__ __launch_bounds__(256) void mfma_logits_conv_k(
    const u16* __restrict__ H, const float* __restrict__ WoutF,
    const float* __restrict__ bout, const int* __restrict__ caption,
    float* __restrict__ psum, float* __restrict__ tlog) {
  __shared__ __align__(16) char smem[16384];
  u16* sA = (u16*)smem;
  u16* sB = (u16*)(smem + 8192);
  const int tid = threadIdx.x;
  int vt, mt;
  logits_decode(blockIdx.x, vt, mt);
  if (mt >= 62) return;
  const int n0 = vt * VT_, m0 = mt * 128;
  const int l = tid & 63, wid = tid >> 6;
  const int wm = (wid & 1) * 64, wn = (wid >> 1) * 64;
  const int q = l >> 4, ln = l & 15;
  f32x4 acc[4][4];
  const f32x4 z = {0.f, 0.f, 0.f, 0.f};
#pragma unroll
  for (int i = 0; i < 4; ++i)
#pragma unroll
    for (int j = 0; j < 4; ++j) acc[i][j] = z;
  const int srow = tid >> 2, scol = (tid & 3) * 8;
  int brow[2];
#pragma unroll
  for (int r = 0; r < 2; ++r) {
    int gr = n0 + srow + r * 64;
    brow[r] = (gr > VOCAB_ - 1) ? (VOCAB_ - 1) : gr;
  }
  for (int k0 = 0; k0 < MEM_; k0 += 32) {
#pragma unroll
    for (int r = 0; r < 2; ++r)
      async16(H + (size_t)(m0 + srow + r * 64) * MEM_ + k0 + scol,
              sA + (srow + r * 64) * 32 + scol);
#pragma unroll
    for (int r = 0; r < 2; ++r) {
      const float* g = WoutF + (size_t)brow[r] * MEM_ + k0 + scol;
      float4 v0 = *(const float4_ma*)g;
      float4 v1 = *(const float4_ma*)(g + 4);
      u16x8 o = { f2bf(v0.x), f2bf(v0.y), f2bf(v0.z), f2bf(v0.w),
                  f2bf(v1.x), f2bf(v1.y), f2bf(v1.z), f2bf(v1.w) };
      *(u16x8_ma*)(sB + (srow + r * 64) * 32 + scol) = o;
    }
    __syncthreads();
    bf16x8 a[4], b[4];
#pragma unroll
    for (int i = 0; i < 4; ++i) a[i] = *(const bf16x8_ma*)(sA + (wm + i * 16 + ln) * 32 + q * 8);
#pragma unroll
    for (int j = 0; j < 4; ++j) b[j] = *(const bf16x8_ma*)(sB + (wn + j * 16 + ln) * 32 + q * 8);
#pragma unroll
    for (int i = 0; i < 4; ++i)
#pragma unroll
      for (int j = 0; j < 4; ++j)
        acc[i][j] = __builtin_amdgcn_mfma_f32_16x16x32_bf16(a[i], b[j], acc[i][j], 0, 0, 0);
    __syncthreads();
  }
  float* eS = (float*)smem;
  float* eT = eS + 256;
  const int half = wid >> 1;
  int colj[4]; float bj[4];
#pragma unroll
  for (int j = 0; j < 4; ++j) {
    colj[j] = n0 + wn + j * 16 + ln;
    bj[j] = (colj[j] < VOCAB_) ? bout[colj[j]] : 0.f;
  }
#pragma unroll
  for (int i = 0; i < 4; ++i) {
#pragma unroll
    for (int r = 0; r < 4; ++r) {
      const int rloc = wm + i * 16 + q * 4 + r;
      const int trow = m0 + rloc;
      const int tgt = caption[(trow & 255) * TT_ + (trow >> 8) + 1];
      float s = 0.f, tv = 0.f;
#pragma unroll
      for (int j = 0; j < 4; ++j) {
        if (colj[j] < VOCAB_) {
          float v = acc[i][j][r] + bj[j];
          s += __expf(v);
          if (colj[j] == tgt) tv += v;
        }
      }
      s = redsum16(s);
      tv = redsum16(tv);
      if (ln == 0) { eS[rloc * 2 + half] = s; eT[rloc * 2 + half] = tv; }
    }
  }
  __syncthreads();
  if (tid < 128) {
    int trow = m0 + tid;
    psum[(size_t)trow * NTV_ + vt] = eS[tid * 2] + eS[tid * 2 + 1];
    int tgt = caption[(trow & 255) * TT_ + (trow >> 8) + 1];
    if (tgt >= n0 && tgt < n0 + VT_) tlog[trow] = eT[tid * 2] + eT[tid * 2 + 1];
  }
}

// ---------------------------------------------------------------------------
__global__ __launch_bounds__(256) void combine_k(
    const float* __restrict__ psum, const float* __restrict__ tlog,
    const int* __restrict__ caption, float* __restrict__ accum) {
  int r = blockIdx.x * 256 + threadIdx.x;
  if (r >= MROWS_) return;
  const float* ps = psum + (size_t)r * NTV_;
  float s = 0.f;
  for (int j = 0; j < NTV_; ++j) s += ps[j];
  float nll = __logf(s) - tlog[r];
  int tgt = caption[(r & 255) * TT_ + (r >> 8) + 1];
  if (tgt != 0) {
    atomicAdd(&accum[0], nll);
    atomicAdd(&accum[1], 1.f);
  }
}

__global__ void zero_words_k(unsigned* buf) {
  buf[threadIdx.x] = 0u;
}

__global__ void finalize_k(const float* __restrict__ accum, float* __restrict__ out) {
  out[0] = accum[0] / fmaxf(accum[1], 1.0f);
}

// ---------------------------------------------------------------------------
extern "C" void kernel_launch(void* const* d_in, const int* in_sizes, int n_in,
                              void* d_out, int out_size, void* d_ws, size_t ws_size,
                              hipStream_t stream) {
  (void)in_sizes; (void)n_in; (void)out_size;
  const float* feature  = (const float*)d_in[0];
  const int*   caption  = (const int*)d_in[1];
  const float* W_init_h = (const float*)d_in[3];
  const float* b_init_h = (const float*)d_in[4];
  const float* W_init_c = (const float*)d_in[5];
  const float* b_init_c = (const float*)d_in[6];
  const float* emb      = (const float*)d_in[7];
  const float* W_ih     = (const float*)d_in[8];
  const float* b_ih     = (const float*)d_in[9];
  const float* W_hh     = (const float*)d_in[10];
  const float* b_hh     = (const float*)d_in[11];
  const float* W_out    = (const float*)d_in[12];
  const float* b_out    = (const float*)d_in[13];
  float* out = (float*)d_out;

  char* p = (char*)d_ws;
  u16* WPih = (u16*)p;       p += (size_t)4096 * 512 * 2;
  u16* WPhh = (u16*)p;       p += (size_t)4096 * 1024 * 2;
  float* biasP = (float*)p;  p += (size_t)4096 * 4;
  u16* Xall = (u16*)p;       p += (size_t)NSTEP * 256 * 512 * 2;
  u16* Hall = (u16*)p;       p += (size_t)32 * 256 * 1024 * 2;
  float* c0 = (float*)p;     p += (size_t)256 * 1024 * 4;
  float* psum = (float*)p;   p += (size_t)MROWS_ * NTV_ * 4;
  float* tlog = (float*)p;   p += (size_t)MROWS_ * 4;
  unsigned* syncbuf = (unsigned*)p; p += 256;
  u16* WoutB = (u16*)p;      p += (size_t)VOCAB_ * 1024 * 2;
  size_t woutEnd = (size_t)(p - (char*)d_ws);
  u16* featB = (u16*)p;      p += (size_t)256 * 2048 * 2;
  u16* WinitHB = (u16*)p;    p += (size_t)1024 * 2048 * 2;
  u16* WinitCB = (u16*)p;    p += (size_t)1024 * 2048 * 2;
  size_t initEnd = (size_t)(p - (char*)d_ws);

  bool haveWoutB = (ws_size >= woutEnd);
  bool haveInitB = (ws_size >= initEnd);

  float* accum = (float*)syncbuf;

  dim3 blk(256);
  zero_words_k<<<1, 64, 0, stream>>>(syncbuf);
  cvt_permute_k<<<4096, 128, 0, stream>>>(W_ih, W_hh, b_ih, b_hh, WPih, WPhh, biasP);
  gather_x_k<<<3968, blk, 0, stream>>>(emb, caption, Xall);
  if (haveWoutB) cvt_bf16_k<<<10000, blk, 0, stream>>>(W_out, WoutB, 2560000);

  if (haveInitB) {
    cvt_bf16_k<<<512, blk, 0, stream>>>(feature, featB, 131072);
    cvt_bf16_k<<<2048, blk, 0, stream>>>(W_init_h, WinitHB, 524288);
    cvt_bf16_k<<<2048, blk, 0, stream>>>(W_init_c, WinitCB, 524288);
    dim3 gi(16, 4);
    mfma_init_k<<<gi, blk, 0, stream>>>(featB, WinitHB, b_init_h, Hall, nullptr);
    mfma_init_k<<<gi, blk, 0, stream>>>(featB, WinitCB, b_init_c, nullptr, c0);
  } else {
    dim3 gi(16, 4);
    gemm_nt_bias_k<<<gi, blk, 0, stream>>>(feature, W_init_h, b_init_h, nullptr, Hall,
                                           BS_, MEM_, FEAT_);
    gemm_nt_bias_k<<<gi, blk, 0, stream>>>(feature, W_init_c, b_init_c, c0, nullptr,
                                           BS_, MEM_, FEAT_);
  }

  for (int t = 0; t < NSTEP; ++t) {
    lstm_step_k<<<256, blk, 0, stream>>>(Xall + (size_t)t * BS_ * EMB_,
                                         Hall + (size_t)t * BS_ * MEM_,
                                         Hall + (size_t)(t + 1) * BS_ * MEM_,
                                         WPih, WPhh, biasP, c0);
  }

  const int LGRID = 8 * 8 * NTV_;   // 5056: xcd(8) x mt-band(8) x vt(79)
  if (haveWoutB)
    mfma_logits_k<<<LGRID, blk, 0, stream>>>(Hall + (size_t)BS_ * MEM_, WoutB,
                                             b_out, caption, psum, tlog);
  else
    mfma_logits_conv_k<<<LGRID, blk, 0, stream>>>(Hall + (size_t)BS_ * MEM_, W_out,
                                                  b_out, caption, psum, tlog);

  combine_k<<<31, blk, 0, stream>>>(psum, tlog, caption, accum);
  finalize_k<<<1, 1, 0, stream>>>(accum, out);
}

// Round 7
// 765.164 us; speedup vs baseline: 2.2425x; 1.0072x over previous
//
#include <hip/hip_runtime.h>
#include <math.h>

#define BS_    256
#define FEAT_  2048
#define EMB_   512
#define MEM_   1024
#define VOCAB_ 10000
#define TT_    32
#define NSTEP  31
#define VT_    128
#define NTV_   79      // ceil(10000/128)
#define MROWS_ 7936    // 31*256
#define PAD_   40      // init LDS row stride (bf16 elems)
#define SP_    72      // step LDS row stride: 36 dwords -> quad=(r+q)%8 -> 2-way (free)

typedef unsigned short u16;
typedef __bf16 bf16x8 __attribute__((ext_vector_type(8)));
typedef float  f32x4  __attribute__((ext_vector_type(4)));
typedef u16    u16x8  __attribute__((ext_vector_type(8)));
typedef u16    u16x4  __attribute__((ext_vector_type(4)));
typedef bf16x8 __attribute__((may_alias)) bf16x8_ma;
typedef u16x8  __attribute__((may_alias)) u16x8_ma;
typedef u16x4  __attribute__((may_alias)) u16x4_ma;
typedef float4 __attribute__((may_alias)) float4_ma;

__device__ __forceinline__ u16 f2bf(float f) {
  unsigned u = __float_as_uint(f);
  u += 0x7FFFu + ((u >> 16) & 1u);
  return (u16)(u >> 16);
}

__device__ __forceinline__ void async16(const void* g, void* s) {
  __builtin_amdgcn_global_load_lds((const __attribute__((address_space(1))) void*)g,
                                   (__attribute__((address_space(3))) void*)s, 16, 0, 0);
}

__device__ __forceinline__ float redsum16(float v) {
#pragma unroll
  for (int m = 1; m < 16; m <<= 1) v += __shfl_xor(v, m, 64);
  return v;
}
__device__ __forceinline__ float sigmoidf_(float x) { return 1.0f / (1.0f + __expf(-x)); }
__device__ __forceinline__ float tanhf_(float x) {
  float e = __expf(2.0f * x);
  return 1.0f - 2.0f / (e + 1.0f);
}

// ---------------------------------------------------------------------------
__global__ __launch_bounds__(256) void cvt_bf16_k(const float* __restrict__ in,
                                                  u16* __restrict__ out, int n4) {
  int i = blockIdx.x * 256 + threadIdx.x;
  if (i >= n4) return;
  float4 v = ((const float4_ma*)in)[i];
  u16x4 o = { f2bf(v.x), f2bf(v.y), f2bf(v.z), f2bf(v.w) };
  *(u16x4_ma*)(out + (size_t)i * 4) = o;
}

// ---------------------------------------------------------------------------
// Gate-permuted weights: permuted row r -> source row (r&3)*1024+(r>>2)
// ---------------------------------------------------------------------------
__global__ __launch_bounds__(128) void cvt_permute_k(
    const float* __restrict__ W_ih, const float* __restrict__ W_hh,
    const float* __restrict__ b_ih, const float* __restrict__ b_hh,
    u16* __restrict__ WPih, u16* __restrict__ WPhh, float* __restrict__ biasP) {
  int r = blockIdx.x, tid = threadIdx.x;
  int u = r >> 2, g = r & 3, s = g * 1024 + u;
  {
    float4 v = *(const float4_ma*)(W_ih + (size_t)s * EMB_ + tid * 4);
    u16x4 o = { f2bf(v.x), f2bf(v.y), f2bf(v.z), f2bf(v.w) };
    *(u16x4_ma*)(WPih + (size_t)r * EMB_ + tid * 4) = o;
  }
#pragma unroll
  for (int h = 0; h < 2; ++h) {
    int idx = h * 512 + tid * 4;
    float4 v = *(const float4_ma*)(W_hh + (size_t)s * MEM_ + idx);
    u16x4 o = { f2bf(v.x), f2bf(v.y), f2bf(v.z), f2bf(v.w) };
    *(u16x4_ma*)(WPhh + (size_t)r * MEM_ + idx) = o;
  }
  if (tid == 0) biasP[r] = b_ih[s] + b_hh[s];
}

// ---------------------------------------------------------------------------
__global__ __launch_bounds__(256) void gather_x_k(const float* __restrict__ emb,
                                                  const int* __restrict__ caption,
                                                  u16* __restrict__ X) {
  int i = blockIdx.x * 256 + threadIdx.x;
  int e4 = (i & 127) * 4;
  int b  = (i >> 7) & 255;
  int t  = i >> 15;
  int cap = caption[b * TT_ + t];
  float4 v = *(const float4_ma*)(emb + (size_t)cap * EMB_ + e4);
  u16x4 o = { f2bf(v.x), f2bf(v.y), f2bf(v.z), f2bf(v.w) };
  *(u16x4_ma*)(X + ((size_t)(t * 256 + b) * EMB_ + e4)) = o;
}

// ---------------------------------------------------------------------------
// fp32 vector GEMM fallback for init
// ---------------------------------------------------------------------------
__global__ __launch_bounds__(256) void gemm_nt_bias_k(
    const float* __restrict__ A, const float* __restrict__ B,
    const float* __restrict__ bias, float* __restrict__ C, u16* __restrict__ Cb,
    int M, int N, int K) {
  __shared__ float As[16][65];
  __shared__ float Bs[16][65];
  int tid = threadIdx.x;
  int bx = blockIdx.x, by = blockIdx.y;
  int tx = tid & 15, ty = tid >> 4;
  float acc[4][4] = {};
  for (int k0 = 0; k0 < K; k0 += 16) {
#pragma unroll
    for (int i = 0; i < 4; ++i) {
      int idx = tid + i * 256;
      As[idx & 15][idx >> 4] = A[(size_t)(by * 64 + (idx >> 4)) * K + k0 + (idx & 15)];
    }
#pragma unroll
    for (int i = 0; i < 4; ++i) {
      int idx = tid + i * 256;
      Bs[idx & 15][idx >> 4] = B[(size_t)(bx * 64 + (idx >> 4)) * K + k0 + (idx & 15)];
    }
    __syncthreads();
#pragma unroll
    for (int kk = 0; kk < 16; ++kk) {
      float a[4], b[4];
#pragma unroll
      for (int i = 0; i < 4; ++i) a[i] = As[kk][ty * 4 + i];
#pragma unroll
      for (int j = 0; j < 4; ++j) b[j] = Bs[kk][tx * 4 + j];
#pragma unroll
      for (int i = 0; i < 4; ++i)
#pragma unroll
        for (int j = 0; j < 4; ++j) acc[i][j] += a[i] * b[j];
    }
    __syncthreads();
  }
#pragma unroll
  for (int i = 0; i < 4; ++i) {
    int gm = by * 64 + ty * 4 + i;
#pragma unroll
    for (int j = 0; j < 4; ++j) {
      int gn = bx * 64 + tx * 4 + j;
      float v = acc[i][j] + bias[gn];
      if (C)  C[(size_t)gm * N + gn] = v;
      if (Cb) Cb[(size_t)gm * N + gn] = f2bf(v);
    }
  }
}

// ---------------------------------------------------------------------------
// MFMA init GEMM: 64x64 tile, dbuf reg-prefetch.  Grid (16, 4).
// ---------------------------------------------------------------------------
__global__ __launch_bounds__(256) void mfma_init_k(
    const u16* __restrict__ A, const u16* __restrict__ Bw,
    const float* __restrict__ bias, u16* __restrict__ outB, float* __restrict__ outF) {
  __shared__ __align__(16) u16 sA[2][64 * PAD_];
  __shared__ __align__(16) u16 sB[2][64 * PAD_];
  const int tid = threadIdx.x;
  const int m0 = blockIdx.y * 64, n0 = blockIdx.x * 64;
  const int l = tid & 63, wid = tid >> 6;
  const int wm = (wid & 1) * 32, wn = (wid >> 1) * 32;
  const int q = l >> 4, ln = l & 15;
  const int srow = tid >> 2, scol = (tid & 3) * 8;
  const u16* Ar = A + (size_t)(m0 + srow) * FEAT_ + scol;
  const u16* Br = Bw + (size_t)(n0 + srow) * FEAT_ + scol;

  f32x4 acc[2][2];
  const f32x4 z = {0.f, 0.f, 0.f, 0.f};
  acc[0][0] = z; acc[0][1] = z; acc[1][0] = z; acc[1][1] = z;

  u16x8 ra = *(const u16x8_ma*)Ar;
  u16x8 rb = *(const u16x8_ma*)Br;
  int p = 0;
  for (int it = 0; it < FEAT_ / 32; ++it) {
    *(u16x8_ma*)(sA[p] + srow * PAD_ + scol) = ra;
    *(u16x8_ma*)(sB[p] + srow * PAD_ + scol) = rb;
    __syncthreads();
    if (it + 1 < FEAT_ / 32) {
      ra = *(const u16x8_ma*)(Ar + (it + 1) * 32);
      rb = *(const u16x8_ma*)(Br + (it + 1) * 32);
    }
    bf16x8 a0 = *(const bf16x8_ma*)(sA[p] + (wm + ln) * PAD_ + q * 8);
    bf16x8 a1 = *(const bf16x8_ma*)(sA[p] + (wm + 16 + ln) * PAD_ + q * 8);
    bf16x8 b0 = *(const bf16x8_ma*)(sB[p] + (wn + ln) * PAD_ + q * 8);
    bf16x8 b1 = *(const bf16x8_ma*)(sB[p] + (wn + 16 + ln) * PAD_ + q * 8);
    acc[0][0] = __builtin_amdgcn_mfma_f32_16x16x32_bf16(a0, b0, acc[0][0], 0, 0, 0);
    acc[0][1] = __builtin_amdgcn_mfma_f32_16x16x32_bf16(a0, b1, acc[0][1], 0, 0, 0);
    acc[1][0] = __builtin_amdgcn_mfma_f32_16x16x32_bf16(a1, b0, acc[1][0], 0, 0, 0);
    acc[1][1] = __builtin_amdgcn_mfma_f32_16x16x32_bf16(a1, b1, acc[1][1], 0, 0, 0);
    p ^= 1;
  }
#pragma unroll
  for (int i = 0; i < 2; ++i)
#pragma unroll
    for (int j = 0; j < 2; ++j)
#pragma unroll
      for (int r = 0; r < 4; ++r) {
        int row = m0 + wm + i * 16 + q * 4 + r;
        int col = n0 + wn + j * 16 + ln;
        float v = acc[i][j][r] + bias[col];
        if (outB) outB[(size_t)row * MEM_ + col] = f2bf(v);
        if (outF) outF[(size_t)row * MEM_ + col] = v;
      }
}

// ---------------------------------------------------------------------------
// Fused LSTM step: BK=64 (24 iters), prefetch depth 2, LDS stride 72 (2-way).
// 256 blocks x 256 thr; block -> 64 rows x 64 permuted gate-cols.
// ---------------------------------------------------------------------------
__global__ __launch_bounds__(256) void lstm_step_k(
    const u16* __restrict__ Xt, const u16* __restrict__ Hin,
    u16* __restrict__ Hout,
    const u16* __restrict__ WPih, const u16* __restrict__ WPhh,
    const float* __restrict__ biasP, float* __restrict__ c) {
  __shared__ __align__(16) u16 sA[2][64 * SP_];
  __shared__ __align__(16) u16 sB[2][64 * SP_];
  __shared__ __align__(16) float sG[64 * 68];
  const int tid = threadIdx.x;
  const int b = blockIdx.x;
  const int m0 = (b >> 6) * 64, nt = b & 63;
  const int l = tid & 63, wid = tid >> 6;
  const int wm = (wid & 1) * 32, wn = (wid >> 1) * 32;
  const int q = l >> 4, ln = l & 15;
  const int srow = tid >> 2, scol = (tid & 3) * 8;

  const u16* aX = Xt  + (size_t)(m0 + srow) * EMB_ + scol;
  const u16* aH = Hin + (size_t)(m0 + srow) * MEM_ + scol;
  const u16* bX = WPih + (size_t)(nt * 64 + srow) * EMB_ + scol;
  const u16* bH = WPhh + (size_t)(nt * 64 + srow) * MEM_ + scol;

  const float bj0 = biasP[nt * 64 + wn + ln];
  const float bj1 = biasP[nt * 64 + wn + 16 + ln];

  f32x4 acc[2][2];
  const f32x4 z = {0.f, 0.f, 0.f, 0.f};
  acc[0][0] = z; acc[0][1] = z; acc[1][0] = z; acc[1][1] = z;

  // depth-2 register prefetch
  u16x8 rA[2][2], rB[2][2];
#pragma unroll
  for (int s = 0; s < 2; ++s)
#pragma unroll
    for (int cc = 0; cc < 2; ++cc) {
      int k = s * 64 + cc * 32;   // < 512: embedding region
      rA[s][cc] = *(const u16x8_ma*)(aX + k);
      rB[s][cc] = *(const u16x8_ma*)(bX + k);
    }

  for (int it = 0; it < 24; ++it) {
    const int s = it & 1;
#pragma unroll
    for (int cc = 0; cc < 2; ++cc) {
      *(u16x8_ma*)(sA[s] + srow * SP_ + scol + 32 * cc) = rA[s][cc];
      *(u16x8_ma*)(sB[s] + srow * SP_ + scol + 32 * cc) = rB[s][cc];
    }
    __syncthreads();
    if (it + 2 < 24) {
#pragma unroll
      for (int cc = 0; cc < 2; ++cc) {
        int k = (it + 2) * 64 + cc * 32;
        if (k < EMB_) {
          rA[s][cc] = *(const u16x8_ma*)(aX + k);
          rB[s][cc] = *(const u16x8_ma*)(bX + k);
        } else {
          rA[s][cc] = *(const u16x8_ma*)(aH + (k - EMB_));
          rB[s][cc] = *(const u16x8_ma*)(bH + (k - EMB_));
        }
      }
    }
#pragma unroll
    for (int kk = 0; kk < 2; ++kk) {
      bf16x8 a0 = *(const bf16x8_ma*)(sA[s] + (wm + ln) * SP_ + kk * 32 + q * 8);
      bf16x8 a1 = *(const bf16x8_ma*)(sA[s] + (wm + 16 + ln) * SP_ + kk * 32 + q * 8);
      bf16x8 b0 = *(const bf16x8_ma*)(sB[s] + (wn + ln) * SP_ + kk * 32 + q * 8);
      bf16x8 b1 = *(const bf16x8_ma*)(sB[s] + (wn + 16 + ln) * SP_ + kk * 32 + q * 8);
      acc[0][0] = __builtin_amdgcn_mfma_f32_16x16x32_bf16(a0, b0, acc[0][0], 0, 0, 0);
      acc[0][1] = __builtin_amdgcn_mfma_f32_16x16x32_bf16(a0, b1, acc[0][1], 0, 0, 0);
      acc[1][0] = __builtin_amdgcn_mfma_f32_16x16x32_bf16(a1, b0, acc[1][0], 0, 0, 0);
      acc[1][1] = __builtin_amdgcn_mfma_f32_16x16x32_bf16(a1, b1, acc[1][1], 0, 0, 0);
    }
  }

  // gate tile -> sG
#pragma unroll
  for (int i = 0; i < 2; ++i)
#pragma unroll
    for (int j = 0; j < 2; ++j)
#pragma unroll
      for (int r = 0; r < 4; ++r)
        sG[(wm + i * 16 + q * 4 + r) * 68 + wn + j * 16 + ln] =
            acc[i][j][r] + (j ? bj1 : bj0);
  __syncthreads();

  // pointwise: thread -> (row, 4 units); c in global fp32
  {
    const int prow = tid >> 2, u0 = (tid & 3) * 4;
    const float* gRow = sG + prow * 68 + u0 * 4;
    float* cp = c + (size_t)(m0 + prow) * MEM_ + nt * 16 + u0;
    float4 cv = *(const float4_ma*)cp;
    float cva[4] = {cv.x, cv.y, cv.z, cv.w};
    u16x4 hv;
    float cna[4];
#pragma unroll
    for (int k = 0; k < 4; ++k) {
      float4 g4 = *(const float4_ma*)(gRow + k * 4);   // (i,f,g,o)
      float cvn = sigmoidf_(g4.y) * cva[k] + sigmoidf_(g4.x) * tanhf_(g4.z);
      cna[k] = cvn;
      hv[k] = f2bf(sigmoidf_(g4.w) * tanhf_(cvn));
    }
    float4 cn = {cna[0], cna[1], cna[2], cna[3]};
    *(float4_ma*)cp = cn;
    *(u16x4_ma*)(Hout + (size_t)(m0 + prow) * MEM_ + nt * 16 + u0) = hv;
  }
}

// ---------------------------------------------------------------------------
// XCD-banded grid decode (kept from r6: FETCH_SIZE 648->94 MB)
// ---------------------------------------------------------------------------
__device__ __forceinline__ void logits_decode(int bid, int& vt, int& mt) {
  int xcd = bid & 7, s = bid >> 3;
  vt = s >> 3;
  mt = xcd * 8 + (s & 7);
}

// ---------------------------------------------------------------------------
// Logits GEMM + fused sum-exp partials, m97-style: global_load_lds staging,
// stride-32 LDS (async16 layout constraint), single-buffered, 2 barriers/iter.
// Tile 128x128, 4 waves (64x64 each).  tlog via direct one-lane store.
// ---------------------------------------------------------------------------
__global__ __launch_bounds__(256) void mfma_logits_k(
    const u16* __restrict__ H, const u16* __restrict__ WoutB,
    const float* __restrict__ bout, const int* __restrict__ caption,
    float* __restrict__ psum, float* __restrict__ tlog) {
  __shared__ __align__(16) u16 sA[128 * 32];
  __shared__ __align__(16) u16 sB[128 * 32];
  const int tid = threadIdx.x;
  int vt, mt;
  logits_decode(blockIdx.x, vt, mt);
  if (mt >= 62) return;
  const int n0 = vt * VT_, m0 = mt * 128;
  const int l = tid & 63, wid = tid >> 6;
  const int wm = (wid & 1) * 64, wn = (wid >> 1) * 64;
  const int q = l >> 4, ln = l & 15;

  f32x4 acc[4][4];
  const f32x4 z = {0.f, 0.f, 0.f, 0.f};
#pragma unroll
  for (int i = 0; i < 4; ++i)
#pragma unroll
    for (int j = 0; j < 4; ++j) acc[i][j] = z;

  // staging addresses: thread covers row (tid>>2)+64r, 16B chunk (tid&3)
  const int srow = tid >> 2, scol = (tid & 3) * 8;
  int brow[2];
#pragma unroll
  for (int r = 0; r < 2; ++r) {
    int gr = n0 + srow + r * 64;
    brow[r] = (gr > VOCAB_ - 1) ? (VOCAB_ - 1) : gr;
  }
  const u16* aSrc[2] = { H + (size_t)(m0 + srow) * MEM_ + scol,
                         H + (size_t)(m0 + srow + 64) * MEM_ + scol };
  const u16* bSrc[2] = { WoutB + (size_t)brow[0] * MEM_ + scol,
                         WoutB + (size_t)brow[1] * MEM_ + scol };
  u16* aDst[2] = { sA + srow * 32 + scol, sA + (srow + 64) * 32 + scol };
  u16* bDst[2] = { sB + srow * 32 + scol, sB + (srow + 64) * 32 + scol };

  for (int k0 = 0; k0 < MEM_; k0 += 32) {
#pragma unroll
    for (int r = 0; r < 2; ++r) {
      async16(aSrc[r] + k0, aDst[r]);
      async16(bSrc[r] + k0, bDst[r]);
    }
    __syncthreads();
    bf16x8 a[4], b[4];
#pragma unroll
    for (int i = 0; i < 4; ++i) a[i] = *(const bf16x8_ma*)(sA + (wm + i * 16 + ln) * 32 + q * 8);
#pragma unroll
    for (int j = 0; j < 4; ++j) b[j] = *(const bf16x8_ma*)(sB + (wn + j * 16 + ln) * 32 + q * 8);
#pragma unroll
    for (int i = 0; i < 4; ++i)
#pragma unroll
      for (int j = 0; j < 4; ++j)
        acc[i][j] = __builtin_amdgcn_mfma_f32_16x16x32_bf16(a[i], b[j], acc[i][j], 0, 0, 0);
    __syncthreads();
  }

  // ---- fused sum-exp epilogue (reuse sA as float scratch) ----
  float* eS = (float*)sA;          // [128][2]
  const int half = wid >> 1;

  int colj[4]; float bj[4];
#pragma unroll
  for (int j = 0; j < 4; ++j) {
    colj[j] = n0 + wn + j * 16 + ln;
    bj[j] = (colj[j] < VOCAB_) ? bout[colj[j]] : 0.f;
  }
#pragma unroll
  for (int i = 0; i < 4; ++i) {
#pragma unroll
    for (int r = 0; r < 4; ++r) {
      const int rloc = wm + i * 16 + q * 4 + r;
      const int trow = m0 + rloc;
      const int tgt = caption[(trow & 255) * TT_ + (trow >> 8) + 1];
      float s = 0.f;
#pragma unroll
      for (int j = 0; j < 4; ++j) {
        if (colj[j] < VOCAB_) {
          float v = acc[i][j][r] + bj[j];
          s += __expf(v);
          if (colj[j] == tgt) tlog[trow] = v;   // exactly one lane device-wide
        }
      }
      s = redsum16(s);
      if (ln == 0) eS[rloc * 2 + half] = s;
    }
  }
  __syncthreads();
  if (tid < 128) {
    int trow = m0 + tid;
    psum[(size_t)trow * NTV_ + vt] = eS[tid * 2] + eS[tid * 2 + 1];
  }
}

// ---------------------------------------------------------------------------
// Fallback logits (fp32 W_out staged inline through LDS) — only if ws small.
// ---------------------------------------------------------------------------
__global__ __launch_bounds__(256) void mfma_logits_conv_k(
    const u16* __restrict__ H, const float* __restrict__ WoutF,
    const float* __restrict__ bout, const int* __restrict__ caption,
    float* __restrict__ psum, float* __restrict__ tlog) {
  __shared__ __align__(16) char smem[16384];
  u16* sA = (u16*)smem;
  u16* sB = (u16*)(smem + 8192);
  const int tid = threadIdx.x;
  int vt, mt;
  logits_decode(blockIdx.x, vt, mt);
  if (mt >= 62) return;
  const int n0 = vt * VT_, m0 = mt * 128;
  const int l = tid & 63, wid = tid >> 6;
  const int wm = (wid & 1) * 64, wn = (wid >> 1) * 64;
  const int q = l >> 4, ln = l & 15;
  f32x4 acc[4][4];
  const f32x4 z = {0.f, 0.f, 0.f, 0.f};
#pragma unroll
  for (int i = 0; i < 4; ++i)
#pragma unroll
    for (int j = 0; j < 4; ++j) acc[i][j] = z;
  const int srow = tid >> 2, scol = (tid & 3) * 8;
  int brow[2];
#pragma unroll
  for (int r = 0; r < 2; ++r) {
    int gr = n0 + srow + r * 64;
    brow[r] = (gr > VOCAB_ - 1) ? (VOCAB_ - 1) : gr;
  }
  for (int k0 = 0; k0 < MEM_; k0 += 32) {
#pragma unroll
    for (int r = 0; r < 2; ++r)
      async16(H + (size_t)(m0 + srow + r * 64) * MEM_ + k0 + scol,
              sA + (srow + r * 64) * 32 + scol);
#pragma unroll
    for (int r = 0; r < 2; ++r) {
      const float* g = WoutF + (size_t)brow[r] * MEM_ + k0 + scol;
      float4 v0 = *(const float4_ma*)g;
      float4 v1 = *(const float4_ma*)(g + 4);
      u16x8 o = { f2bf(v0.x), f2bf(v0.y), f2bf(v0.z), f2bf(v0.w),
                  f2bf(v1.x), f2bf(v1.y), f2bf(v1.z), f2bf(v1.w) };
      *(u16x8_ma*)(sB + (srow + r * 64) * 32 + scol) = o;
    }
    __syncthreads();
    bf16x8 a[4], b[4];
#pragma unroll
    for (int i = 0; i < 4; ++i) a[i] = *(const bf16x8_ma*)(sA + (wm + i * 16 + ln) * 32 + q * 8);
#pragma unroll
    for (int j = 0; j < 4; ++j) b[j] = *(const bf16x8_ma*)(sB + (wn + j * 16 + ln) * 32 + q * 8);
#pragma unroll
    for (int i = 0; i < 4; ++i)
#pragma unroll
      for (int j = 0; j < 4; ++j)
        acc[i][j] = __builtin_amdgcn_mfma_f32_16x16x32_bf16(a[i], b[j], acc[i][j], 0, 0, 0);
    __syncthreads();
  }
  float* eS = (float*)smem;
  const int half = wid >> 1;
  int colj[4]; float bj[4];
#pragma unroll
  for (int j = 0; j < 4; ++j) {
    colj[j] = n0 + wn + j * 16 + ln;
    bj[j] = (colj[j] < VOCAB_) ? bout[colj[j]] : 0.f;
  }
#pragma unroll
  for (int i = 0; i < 4; ++i) {
#pragma unroll
    for (int r = 0; r < 4; ++r) {
      const int rloc = wm + i * 16 + q * 4 + r;
      const int trow = m0 + rloc;
      const int tgt = caption[(trow & 255) * TT_ + (trow >> 8) + 1];
      float s = 0.f;
#pragma unroll
      for (int j = 0; j < 4; ++j) {
        if (colj[j] < VOCAB_) {
          float v = acc[i][j][r] + bj[j];
          s += __expf(v);
          if (colj[j] == tgt) tlog[trow] = v;
        }
      }
      s = redsum16(s);
      if (ln == 0) eS[rloc * 2 + half] = s;
    }
  }
  __syncthreads();
  if (tid < 128) {
    int trow = m0 + tid;
    psum[(size_t)trow * NTV_ + vt] = eS[tid * 2] + eS[tid * 2 + 1];
  }
}

// ---------------------------------------------------------------------------
__global__ __launch_bounds__(256) void combine_k(
    const float* __restrict__ psum, const float* __restrict__ tlog,
    const int* __restrict__ caption, float* __restrict__ accum) {
  int r = blockIdx.x * 256 + threadIdx.x;
  if (r >= MROWS_) return;
  const float* ps = psum + (size_t)r * NTV_;
  float s = 0.f;
  for (int j = 0; j < NTV_; ++j) s += ps[j];
  float nll = __logf(s) - tlog[r];
  int tgt = caption[(r & 255) * TT_ + (r >> 8) + 1];
  if (tgt != 0) {
    atomicAdd(&accum[0], nll);
    atomicAdd(&accum[1], 1.f);
  }
}

__global__ void zero_words_k(unsigned* buf) {
  buf[threadIdx.x] = 0u;
}

__global__ void finalize_k(const float* __restrict__ accum, float* __restrict__ out) {
  out[0] = accum[0] / fmaxf(accum[1], 1.0f);
}

// ---------------------------------------------------------------------------
extern "C" void kernel_launch(void* const* d_in, const int* in_sizes, int n_in,
                              void* d_out, int out_size, void* d_ws, size_t ws_size,
                              hipStream_t stream) {
  (void)in_sizes; (void)n_in; (void)out_size;
  const float* feature  = (const float*)d_in[0];
  const int*   caption  = (const int*)d_in[1];
  const float* W_init_h = (const float*)d_in[3];
  const float* b_init_h = (const float*)d_in[4];
  const float* W_init_c = (const float*)d_in[5];
  const float* b_init_c = (const float*)d_in[6];
  const float* emb      = (const float*)d_in[7];
  const float* W_ih     = (const float*)d_in[8];
  const float* b_ih     = (const float*)d_in[9];
  const float* W_hh     = (const float*)d_in[10];
  const float* b_hh     = (const float*)d_in[11];
  const float* W_out    = (const float*)d_in[12];
  const float* b_out    = (const float*)d_in[13];
  float* out = (float*)d_out;

  char* p = (char*)d_ws;
  u16* WPih = (u16*)p;       p += (size_t)4096 * 512 * 2;
  u16* WPhh = (u16*)p;       p += (size_t)4096 * 1024 * 2;
  float* biasP = (float*)p;  p += (size_t)4096 * 4;
  u16* Xall = (u16*)p;       p += (size_t)NSTEP * 256 * 512 * 2;
  u16* Hall = (u16*)p;       p += (size_t)32 * 256 * 1024 * 2;
  float* c0 = (float*)p;     p += (size_t)256 * 1024 * 4;
  float* psum = (float*)p;   p += (size_t)MROWS_ * NTV_ * 4;
  float* tlog = (float*)p;   p += (size_t)MROWS_ * 4;
  unsigned* syncbuf = (unsigned*)p; p += 256;
  u16* WoutB = (u16*)p;      p += (size_t)VOCAB_ * 1024 * 2;
  size_t woutEnd = (size_t)(p - (char*)d_ws);
  u16* featB = (u16*)p;      p += (size_t)256 * 2048 * 2;
  u16* WinitHB = (u16*)p;    p += (size_t)1024 * 2048 * 2;
  u16* WinitCB = (u16*)p;    p += (size_t)1024 * 2048 * 2;
  size_t initEnd = (size_t)(p - (char*)d_ws);

  bool haveWoutB = (ws_size >= woutEnd);
  bool haveInitB = (ws_size >= initEnd);

  float* accum = (float*)syncbuf;

  dim3 blk(256);
  zero_words_k<<<1, 64, 0, stream>>>(syncbuf);
  cvt_permute_k<<<4096, 128, 0, stream>>>(W_ih, W_hh, b_ih, b_hh, WPih, WPhh, biasP);
  gather_x_k<<<3968, blk, 0, stream>>>(emb, caption, Xall);
  if (haveWoutB) cvt_bf16_k<<<10000, blk, 0, stream>>>(W_out, WoutB, 2560000);

  if (haveInitB) {
    cvt_bf16_k<<<512, blk, 0, stream>>>(feature, featB, 131072);
    cvt_bf16_k<<<2048, blk, 0, stream>>>(W_init_h, WinitHB, 524288);
    cvt_bf16_k<<<2048, blk, 0, stream>>>(W_init_c, WinitCB, 524288);
    dim3 gi(16, 4);
    mfma_init_k<<<gi, blk, 0, stream>>>(featB, WinitHB, b_init_h, Hall, nullptr);
    mfma_init_k<<<gi, blk, 0, stream>>>(featB, WinitCB, b_init_c, nullptr, c0);
  } else {
    dim3 gi(16, 4);
    gemm_nt_bias_k<<<gi, blk, 0, stream>>>(feature, W_init_h, b_init_h, nullptr, Hall,
                                           BS_, MEM_, FEAT_);
    gemm_nt_bias_k<<<gi, blk, 0, stream>>>(feature, W_init_c, b_init_c, c0, nullptr,
                                           BS_, MEM_, FEAT_);
  }

  for (int t = 0; t < NSTEP; ++t) {
    lstm_step_k<<<256, blk, 0, stream>>>(Xall + (size_t)t * BS_ * EMB_,
                                         Hall + (size_t)t * BS_ * MEM_,
                                         Hall + (size_t)(t + 1) * BS_ * MEM_,
                                         WPih, WPhh, biasP, c0);
  }

  const int LGRID = 8 * 8 * NTV_;   // 5056: xcd(8) x mt-band(8) x vt(79)
  if (haveWoutB)
    mfma_logits_k<<<LGRID, blk, 0, stream>>>(Hall + (size_t)BS_ * MEM_, WoutB,
                                             b_out, caption, psum, tlog);
  else
    mfma_logits_conv_k<<<LGRID, blk, 0, stream>>>(Hall + (size_t)BS_ * MEM_, W_out,
                                                  b_out, caption, psum, tlog);

  combine_k<<<31, blk, 0, stream>>>(psum, tlog, caption, accum);
  finalize_k<<<1, 1, 0, stream>>>(accum, out);
}